// Round 1
// baseline (351.037 us; speedup 1.0000x reference)
//
#include <hip/hip_runtime.h>
#include <hip/hip_bf16.h>

#define B_DIM 32
#define C_DIM 512
#define T_IN 1024
#define T_OUT 4096

// Kernel 1: per batch row, scan durations -> expand into index map idx[b, t].
// One block per batch row. 256 threads, 4 durations each (T_IN = 1024).
__global__ __launch_bounds__(256) void build_idx_kernel(
    const int* __restrict__ dur, int* __restrict__ idx) {
    __shared__ int s_part[256];

    const int b = blockIdx.x;
    const int tid = threadIdx.x;

    // Load 4 durations per thread (coalesced int4).
    int4 v = ((const int4*)(dur + b * T_IN))[tid];
    int local = v.x + v.y + v.z + v.w;

    // Hillis-Steele inclusive scan over the 256 per-thread partial sums.
    s_part[tid] = local;
    __syncthreads();
    #pragma unroll
    for (int off = 1; off < 256; off <<= 1) {
        int val = s_part[tid];
        int add = (tid >= off) ? s_part[tid - off] : 0;
        __syncthreads();
        s_part[tid] = val + add;
        __syncthreads();
    }
    // Exclusive prefix for this thread's first duration.
    int start = s_part[tid] - local;

    // Expand: source position j repeats dur[j] times starting at its
    // exclusive cumsum. Durations sum exactly to T_OUT, so the whole
    // idx row is overwritten every call (ws is re-poisoned by harness).
    int* row = idx + b * T_OUT;
    int j0 = tid * 4;
    #pragma unroll
    for (int k = 0; k < 4; ++k) {
        int dk = (k == 0) ? v.x : (k == 1) ? v.y : (k == 2) ? v.z : v.w;
        for (int r = 0; r < dk; ++r) {
            row[start + r] = j0 + k;
        }
        start += dk;
    }
}

// Kernel 2: gather. One thread per float4 of output.
// out[b, c, t] = enc[b, c, idx[b, t]]
__global__ __launch_bounds__(256) void gather_kernel(
    const float* __restrict__ enc, const int* __restrict__ idx,
    float* __restrict__ out) {
    const int gid = blockIdx.x * blockDim.x + threadIdx.x;  // over B*C*T_OUT/4
    const int T4 = T_OUT / 4;                               // 1024

    const int t4 = gid & (T4 - 1);
    const int bc = gid >> 10;           // b*C + c
    const int b = bc >> 9;              // / C_DIM (512)

    int4 j = ((const int4*)(idx + b * T_OUT))[t4];
    const float* row = enc + (size_t)bc * T_IN;

    float4 o;
    o.x = row[j.x];
    o.y = row[j.y];
    o.z = row[j.z];
    o.w = row[j.w];
    ((float4*)out)[gid] = o;
}

extern "C" void kernel_launch(void* const* d_in, const int* in_sizes, int n_in,
                              void* d_out, int out_size, void* d_ws, size_t ws_size,
                              hipStream_t stream) {
    const float* enc = (const float*)d_in[0];   // [B, C, T_IN] f32
    const int* dur = (const int*)d_in[1];       // [B, T_IN] int32
    float* out = (float*)d_out;                 // [B, C, T_OUT] f32
    int* idx = (int*)d_ws;                      // [B, T_OUT] int32 scratch

    build_idx_kernel<<<B_DIM, 256, 0, stream>>>(dur, idx);

    const int total4 = B_DIM * C_DIM * (T_OUT / 4);  // 16,777,216
    gather_kernel<<<total4 / 256, 256, 0, stream>>>(enc, idx, out);
}

// Round 2
// 320.631 us; speedup vs baseline: 1.0948x; 1.0948x over previous
//
#include <hip/hip_runtime.h>
#include <hip/hip_bf16.h>

#define B_DIM 32
#define C_DIM 512
#define T_IN 1024
#define T_OUT 4096

// Kernel 1: per batch row, scan durations -> expand into index map idx[b, t].
// One block per batch row. 256 threads, 4 durations each (T_IN = 1024).
__global__ __launch_bounds__(256) void build_idx_kernel(
    const int* __restrict__ dur, int* __restrict__ idx) {
    __shared__ int s_part[256];

    const int b = blockIdx.x;
    const int tid = threadIdx.x;

    int4 v = ((const int4*)(dur + b * T_IN))[tid];
    int local = v.x + v.y + v.z + v.w;

    // Hillis-Steele inclusive scan over 256 per-thread partials.
    s_part[tid] = local;
    __syncthreads();
    #pragma unroll
    for (int off = 1; off < 256; off <<= 1) {
        int val = s_part[tid];
        int add = (tid >= off) ? s_part[tid - off] : 0;
        __syncthreads();
        s_part[tid] = val + add;
        __syncthreads();
    }
    int start = s_part[tid] - local;  // exclusive prefix

    // Expand: source position j repeats dur[j] times at its exclusive cumsum.
    // Rows sum exactly to T_OUT, so the whole idx row is overwritten.
    int* row = idx + b * T_OUT;
    int j0 = tid * 4;
    #pragma unroll
    for (int k = 0; k < 4; ++k) {
        int dk = (k == 0) ? v.x : (k == 1) ? v.y : (k == 2) ? v.z : v.w;
        for (int r = 0; r < dk; ++r) {
            row[start + r] = j0 + k;
        }
        start += dk;
    }
}

// Kernel 2: gather with LDS-staged source row. One block per (b, c).
// All global traffic is coalesced; the data-dependent gather hits LDS only.
// out[b, c, t] = s_row[idx[b, t]]
__global__ __launch_bounds__(256) void gather_kernel(
    const float* __restrict__ enc, const int* __restrict__ idx,
    float* __restrict__ out) {
    __shared__ float s_row[T_IN];  // 4 KiB: the (b, c) source row

    const int bc = blockIdx.x;          // b*C + c
    const int b = bc >> 9;              // / C_DIM (512)
    const int tid = threadIdx.x;

    // Stage enc row: 1024 floats, one float4 per thread, coalesced.
    ((float4*)s_row)[tid] = ((const float4*)(enc + (size_t)bc * T_IN))[tid];
    __syncthreads();

    const int4* idx_row = (const int4*)(idx + b * T_OUT);  // 1024 int4
    float4* out_row = (float4*)(out + (size_t)bc * T_OUT); // 1024 float4

    // 4 groups of 256 float4s; lanes stay consecutive -> coalesced loads/stores.
    #pragma unroll
    for (int g = 0; g < 4; ++g) {
        const int t4 = g * 256 + tid;
        int4 j = idx_row[t4];
        float4 o;
        o.x = s_row[j.x];
        o.y = s_row[j.y];
        o.z = s_row[j.z];
        o.w = s_row[j.w];
        out_row[t4] = o;
    }
}

extern "C" void kernel_launch(void* const* d_in, const int* in_sizes, int n_in,
                              void* d_out, int out_size, void* d_ws, size_t ws_size,
                              hipStream_t stream) {
    const float* enc = (const float*)d_in[0];   // [B, C, T_IN] f32
    const int* dur = (const int*)d_in[1];       // [B, T_IN] int32
    float* out = (float*)d_out;                 // [B, C, T_OUT] f32
    int* idx = (int*)d_ws;                      // [B, T_OUT] int32 scratch

    build_idx_kernel<<<B_DIM, 256, 0, stream>>>(dur, idx);
    gather_kernel<<<B_DIM * C_DIM, 256, 0, stream>>>(enc, idx, out);
}

// Round 5
// 312.613 us; speedup vs baseline: 1.1229x; 1.0256x over previous
//
#include <hip/hip_runtime.h>
#include <hip/hip_bf16.h>

#define B_DIM 32
#define C_DIM 512
#define T_IN 1024
#define T_OUT 4096
#define CPB 4  // channels per gather block

// Native clang vector types: required by __builtin_nontemporal_load/store
// (HIP_vector_type wrappers are rejected).
typedef float nfloat4 __attribute__((ext_vector_type(4)));
typedef int nint4 __attribute__((ext_vector_type(4)));

// Kernel 1: per batch row, full cumsum in LDS, then output-centric expansion
// via binary search (uniform control flow, coalesced writes).
__global__ __launch_bounds__(256) void build_idx_kernel(
    const int* __restrict__ dur, int* __restrict__ idx) {
    __shared__ int s_cum[T_IN];   // inclusive cumsum of durations
    __shared__ int s_part[256];

    const int b = blockIdx.x;
    const int tid = threadIdx.x;

    nint4 v = ((const nint4*)(dur + b * T_IN))[tid];
    // thread-local inclusive sums
    int c1 = v.x, c2 = c1 + v.y, c3 = c2 + v.z, c4 = c3 + v.w;

    // Hillis-Steele inclusive scan of 256 per-thread totals.
    s_part[tid] = c4;
    __syncthreads();
    #pragma unroll
    for (int off = 1; off < 256; off <<= 1) {
        int val = s_part[tid];
        int add = (tid >= off) ? s_part[tid - off] : 0;
        __syncthreads();
        s_part[tid] = val + add;
        __syncthreads();
    }
    int prefix = s_part[tid] - c4;  // exclusive prefix for this thread

    nint4 cumv;
    cumv.x = prefix + c1;
    cumv.y = prefix + c2;
    cumv.z = prefix + c3;
    cumv.w = prefix + c4;
    ((nint4*)s_cum)[tid] = cumv;
    __syncthreads();

    // Output-centric: j(t) = smallest j with cum[j] > t  (searchsorted 'right').
    // Since cum[1023] == T_OUT > t for all t in [0, T_OUT), the answer lies in
    // [0, 1023]: lower_bound over interval size 1023 resolves in exactly 10
    // steps (1023->511->255->...->1->0). Once lo==hi, P(lo) is true so extra
    // steps are idempotent (hi=mid branch).  [Round 4 bug: hi=1024 start left
    // hi-lo==1 unresolved after 10 steps -> off-by-one indices.]
    int* row = idx + b * T_OUT;
    #pragma unroll
    for (int k = 0; k < 16; ++k) {
        const int t = k * 256 + tid;
        int lo = 0, hi = T_IN - 1;
        #pragma unroll
        for (int s = 0; s < 10; ++s) {
            int mid = (lo + hi) >> 1;
            bool gt = s_cum[mid] > t;
            hi = gt ? mid : hi;
            lo = gt ? lo : mid + 1;
        }
        row[t] = lo;
    }
}

// Kernel 2: gather, CPB channels per block. Stage CPB enc rows in LDS; each
// idx int4 load feeds CPB gathered float4 stores. All global traffic coalesced;
// nontemporal on streamed data (enc read-once, out never re-read) to keep L2
// for the idx rows.
__global__ __launch_bounds__(256) void gather_kernel(
    const float* __restrict__ enc, const int* __restrict__ idx,
    float* __restrict__ out) {
    __shared__ float s_rows[CPB][T_IN];  // 16 KiB

    const int blk = blockIdx.x;          // over B * (C/CPB) = 4096
    const int b = blk >> 7;              // / (C_DIM / CPB = 128)
    const int c0 = (blk & 127) * CPB;
    const int tid = threadIdx.x;

    const float* enc_base = enc + ((size_t)(b * C_DIM + c0)) * T_IN;
    #pragma unroll
    for (int cc = 0; cc < CPB; ++cc) {
        nfloat4 v = __builtin_nontemporal_load(
            ((const nfloat4*)(enc_base + cc * T_IN)) + tid);
        ((nfloat4*)s_rows[cc])[tid] = v;
    }
    __syncthreads();

    const nint4* idx_row = (const nint4*)(idx + b * T_OUT);  // 1024 int4
    float* out_base = out + ((size_t)(b * C_DIM + c0)) * T_OUT;

    #pragma unroll
    for (int g = 0; g < 4; ++g) {
        const int t4 = g * 256 + tid;
        nint4 j = idx_row[t4];
        #pragma unroll
        for (int cc = 0; cc < CPB; ++cc) {
            nfloat4 o;
            o.x = s_rows[cc][j.x];
            o.y = s_rows[cc][j.y];
            o.z = s_rows[cc][j.z];
            o.w = s_rows[cc][j.w];
            __builtin_nontemporal_store(
                o, ((nfloat4*)(out_base + (size_t)cc * T_OUT)) + t4);
        }
    }
}

extern "C" void kernel_launch(void* const* d_in, const int* in_sizes, int n_in,
                              void* d_out, int out_size, void* d_ws, size_t ws_size,
                              hipStream_t stream) {
    const float* enc = (const float*)d_in[0];   // [B, C, T_IN] f32
    const int* dur = (const int*)d_in[1];       // [B, T_IN] int32
    float* out = (float*)d_out;                 // [B, C, T_OUT] f32
    int* idx = (int*)d_ws;                      // [B, T_OUT] int32 scratch

    build_idx_kernel<<<B_DIM, 256, 0, stream>>>(dur, idx);
    gather_kernel<<<B_DIM * (C_DIM / CPB), 256, 0, stream>>>(enc, idx, out);
}